// Round 10
// baseline (208.918 us; speedup 1.0000x reference)
//
#include <hip/hip_runtime.h>
#include <cstdint>
#include <cstddef>

#define TOKENS 8192
#define IN_F   4096
#define OUT_F  4096
#define QMAXF  127.0f
#define EPSF   1e-8f

typedef int i32x4 __attribute__((ext_vector_type(4)));

#define NIT   32                  // iterations; each covers 2 K-halves of 64 B
#define SLOTB 32768               // half-slot: A 16 KB + B 16 KB
#define LDS_TOTAL (4 * SLOTB)     // 131072

__device__ __forceinline__ void gload16(const void* g, void* l) {
    __builtin_amdgcn_global_load_lds(
        (const __attribute__((address_space(1))) void*)g,
        (__attribute__((address_space(3))) void*)l,
        16, 0, 0);
}

__device__ __forceinline__ void bar() {
    asm volatile("" ::: "memory");
    __builtin_amdgcn_s_barrier();
    asm volatile("" ::: "memory");
}

// rule #18: inline-asm lgkmcnt(0) needs a following sched_barrier(0)
__device__ __forceinline__ void lgkm0_fence() {
    asm volatile("s_waitcnt lgkmcnt(0)" ::: "memory");
    __builtin_amdgcn_sched_barrier(0);
}

template <unsigned MASK, unsigned N>
__device__ __forceinline__ void sgb() {
    __builtin_amdgcn_sched_group_barrier(MASK, N, 0);
}

__device__ __forceinline__ int quant1(float v, float inv) {
    int q = (int)rintf(v * inv);
    q = q > 127 ? 127 : q;
    q = q < -127 ? -127 : q;
    return q;
}

__device__ __forceinline__ unsigned int pack4i(int a, int b, int c, int d) {
    return (unsigned int)(a & 255) | ((unsigned int)(b & 255) << 8) |
           ((unsigned int)(c & 255) << 16) | ((unsigned int)(d & 255) << 24);
}

// One block per token: absmax reduce + int8 quantize.
__global__ __launch_bounds__(256) void quant_x_kernel(const float* __restrict__ x,
                                                      signed char* __restrict__ xq,
                                                      float* __restrict__ xscale) {
    const int t   = blockIdx.x;
    const int tid = threadIdx.x;
    const float* xr = x + (size_t)t * IN_F + tid * 16;

    float4 v[4];
    float am = 0.0f;
#pragma unroll
    for (int i = 0; i < 4; ++i) {
        v[i] = ((const float4*)xr)[i];
        am = fmaxf(am, fmaxf(fmaxf(fabsf(v[i].x), fabsf(v[i].y)),
                             fmaxf(fabsf(v[i].z), fabsf(v[i].w))));
    }
#pragma unroll
    for (int off = 32; off >= 1; off >>= 1)
        am = fmaxf(am, __shfl_xor(am, off));

    __shared__ float wmax[4];
    const int wid = tid >> 6, lane = tid & 63;
    if (lane == 0) wmax[wid] = am;
    __syncthreads();
    am = fmaxf(fmaxf(wmax[0], wmax[1]), fmaxf(wmax[2], wmax[3]));

    const float s   = fmaxf(am, EPSF) / QMAXF;
    const float inv = QMAXF / fmaxf(am, EPSF);
    if (tid == 0) xscale[t] = s;

    unsigned int w[4];
#pragma unroll
    for (int i = 0; i < 4; ++i) {
        w[i] = pack4i(quant1(v[i].x, inv), quant1(v[i].y, inv),
                      quant1(v[i].z, inv), quant1(v[i].w, inv));
    }
    *(uint4*)(xq + (size_t)t * IN_F + tid * 16) = make_uint4(w[0], w[1], w[2], w[3]);
}

// Repack int32-held int8 weights into dense int8.
__global__ __launch_bounds__(256) void pack_w_kernel(const int* __restrict__ w,
                                                     signed char* __restrict__ wq) {
    const size_t idx = (size_t)blockIdx.x * 256 + threadIdx.x;
    const int4* src = (const int4*)w + idx * 4;
    unsigned int o[4];
#pragma unroll
    for (int i = 0; i < 4; ++i) {
        int4 u = src[i];
        o[i] = pack4i(u.x, u.y, u.z, u.w);
    }
    ((uint4*)wq)[idx] = make_uint4(o[0], o[1], o[2], o[3]);
}

// R10 = R9 with constant-templated sched_group_barrier.
// 8-phase skeleton + T19 SGB MFMA||ds_read interleave. Reads issued ONE
// PHASE AHEAD of their consuming MFMA cluster, pinned 1:1/1:2 under the
// current cluster's MFMAs; 1 barrier per phase; counted vmcnt(6) twice
// per iteration; 4-slot rotation, stage lead 3 halves.
// Register roles (no copies): P0: mfma(aC,bA) read aN | P1: mfma(aN,bA)
// read bN,aC | P2: mfma(aC,bN) read aN | P3: mfma(aN,bN) read bA,aC.
__global__ __launch_bounds__(512, 2) void gemm_kernel(const signed char* __restrict__ xq,
                                                      const signed char* __restrict__ wq,
                                                      const float* __restrict__ xscale,
                                                      const float* __restrict__ wscale,
                                                      const float* __restrict__ bias,
                                                      float* __restrict__ out) {
    extern __shared__ __align__(16) char lds[];

    const int tid  = threadIdx.x;
    const int wid  = tid >> 6;
    const int lane = tid & 63;
    const int wr   = wid >> 2;   // 0..1
    const int wc   = wid & 3;    // 0..3

    // XCD-aware bijective swizzle (512 blocks, 512 % 8 == 0)
    const int bid = blockIdx.x;
    const int swz = (bid & 7) * 64 + (bid >> 3);
    const int bm0 = (swz >> 4) * 256;   // 32 m-tiles
    const int bn0 = (swz & 15) * 256;   // 16 n-tiles

    // ---- staging map ----
    const int srow = ((tid >> 6) << 4) + (tid & 15);
    const int sgrn = ((tid >> 4) & 3) << 4;
    const signed char* pA = xq + (size_t)(bm0 + srow) * IN_F + sgrn;
    const signed char* pB = wq + (size_t)(bn0 + srow) * IN_F + sgrn;
    const int ldst = tid * 16;

    // ---- fragment read offsets (slot-relative) ----
    const int lrd = (lane >> 4) * 256 + (lane & 15) * 16;
    int a_off[8], b_off[4];
#pragma unroll
    for (int mi = 0; mi < 8; ++mi) a_off[mi] = (wr * 8 + mi) * 1024 + lrd;
#pragma unroll
    for (int ni = 0; ni < 4; ++ni) b_off[ni] = 16384 + (wc * 4 + ni) * 1024 + lrd;

    i32x4 acc[8][4];
#pragma unroll
    for (int mi = 0; mi < 8; ++mi)
#pragma unroll
        for (int ni = 0; ni < 4; ++ni)
#pragma unroll
            for (int r = 0; r < 4; ++r) acc[mi][ni][r] = 0;

    // ---- prologue: stage halves 0,1,2 -> slots 0,1,2 ----
#pragma unroll
    for (int s = 0; s < 3; ++s) {
        char* S = lds + s * SLOTB;
        const int ko = s * 64;
        gload16(pA + ko,                      S + ldst);
        gload16(pA + (size_t)128 * IN_F + ko, S + 8192 + ldst);
        gload16(pB + ko,                      S + 16384 + ldst);
        gload16(pB + (size_t)128 * IN_F + ko, S + 24576 + ldst);
    }
    asm volatile("s_waitcnt vmcnt(8)" ::: "memory");  // half 0 landed
    bar();

    i32x4 aC[4], aN[4], bA[4], bN[4];
#pragma unroll
    for (int ni = 0; ni < 4; ++ni) bA[ni] = *(const i32x4*)(lds + b_off[ni]);
#pragma unroll
    for (int mi = 0; mi < 4; ++mi) aC[mi] = *(const i32x4*)(lds + a_off[mi]);

    for (int t = 0; t < NIT; ++t) {
        const int h = 2 * t;
        const char* S0 = lds + (h & 3) * SLOTB;
        const char* S1 = lds + ((h + 1) & 3) * SLOTB;
        const char* S2 = lds + ((h + 2) & 3) * SLOTB;
        char* G3 = lds + ((h + 3) & 3) * SLOTB;
        char* G4 = lds + ((h + 4) & 3) * SLOTB;
        const int ko3 = (h + 3 < 64 ? h + 3 : 63) * 64;   // clamped: uniform counts
        const int ko4 = (h + 4 < 64 ? h + 4 : 63) * 64;

        // ---------- P0: mfma(aC,bA) -> acc[0..3]; read A4-7(h) -> aN ----------
        lgkm0_fence();
        __builtin_amdgcn_s_setprio(1);
        gload16(pA + ko3,                      G3 + ldst);
        gload16(pA + (size_t)128 * IN_F + ko3, G3 + 8192 + ldst);
#pragma unroll
        for (int mi = 0; mi < 4; ++mi)
#pragma unroll
            for (int ni = 0; ni < 4; ++ni)
                acc[mi][ni] = __builtin_amdgcn_mfma_i32_16x16x64_i8(aC[mi], bA[ni], acc[mi][ni], 0, 0, 0);
#pragma unroll
        for (int mi = 0; mi < 4; ++mi) aN[mi] = *(const i32x4*)(S0 + a_off[4 + mi]);
        sgb<0x30, 2>();
#pragma unroll
        for (int g = 0; g < 4; ++g) { sgb<0x8, 2>(); sgb<0x100, 1>(); }
        sgb<0x8, 8>();
        __builtin_amdgcn_s_setprio(0);
        __builtin_amdgcn_sched_barrier(0);
        asm volatile("s_waitcnt vmcnt(6)" ::: "memory");  // half h+1 landed
        bar();

        // ---------- P1: mfma(aN,bA) -> acc[4..7]; read B(h+1)->bN, A0-3(h+1)->aC ----------
        lgkm0_fence();
        __builtin_amdgcn_s_setprio(1);
        gload16(pB + ko3,                      G3 + 16384 + ldst);
        gload16(pB + (size_t)128 * IN_F + ko3, G3 + 24576 + ldst);
#pragma unroll
        for (int mi = 0; mi < 4; ++mi)
#pragma unroll
            for (int ni = 0; ni < 4; ++ni)
                acc[4 + mi][ni] = __builtin_amdgcn_mfma_i32_16x16x64_i8(aN[mi], bA[ni], acc[4 + mi][ni], 0, 0, 0);
#pragma unroll
        for (int ni = 0; ni < 4; ++ni) bN[ni] = *(const i32x4*)(S1 + b_off[ni]);
#pragma unroll
        for (int mi = 0; mi < 4; ++mi) aC[mi] = *(const i32x4*)(S1 + a_off[mi]);
        sgb<0x30, 2>();
#pragma unroll
        for (int g = 0; g < 8; ++g) { sgb<0x8, 1>(); sgb<0x100, 1>(); }
        sgb<0x8, 8>();
        __builtin_amdgcn_s_setprio(0);
        __builtin_amdgcn_sched_barrier(0);
        bar();

        // ---------- P2: mfma(aC,bN) -> acc[0..3]; read A4-7(h+1) -> aN ----------
        lgkm0_fence();
        __builtin_amdgcn_s_setprio(1);
        gload16(pA + ko4,                      G4 + ldst);
        gload16(pA + (size_t)128 * IN_F + ko4, G4 + 8192 + ldst);
#pragma unroll
        for (int mi = 0; mi < 4; ++mi)
#pragma unroll
            for (int ni = 0; ni < 4; ++ni)
                acc[mi][ni] = __builtin_amdgcn_mfma_i32_16x16x64_i8(aC[mi], bN[ni], acc[mi][ni], 0, 0, 0);
#pragma unroll
        for (int mi = 0; mi < 4; ++mi) aN[mi] = *(const i32x4*)(S1 + a_off[4 + mi]);
        sgb<0x30, 2>();
#pragma unroll
        for (int g = 0; g < 4; ++g) { sgb<0x8, 2>(); sgb<0x100, 1>(); }
        sgb<0x8, 8>();
        __builtin_amdgcn_s_setprio(0);
        __builtin_amdgcn_sched_barrier(0);
        asm volatile("s_waitcnt vmcnt(6)" ::: "memory");  // half h+2 landed
        bar();

        // ---------- P3: mfma(aN,bN) -> acc[4..7]; read B(h+2)->bA, A0-3(h+2)->aC ----------
        lgkm0_fence();
        __builtin_amdgcn_s_setprio(1);
        gload16(pB + ko4,                      G4 + 16384 + ldst);
        gload16(pB + (size_t)128 * IN_F + ko4, G4 + 24576 + ldst);
#pragma unroll
        for (int mi = 0; mi < 4; ++mi)
#pragma unroll
            for (int ni = 0; ni < 4; ++ni)
                acc[4 + mi][ni] = __builtin_amdgcn_mfma_i32_16x16x64_i8(aN[mi], bN[ni], acc[4 + mi][ni], 0, 0, 0);
#pragma unroll
        for (int ni = 0; ni < 4; ++ni) bA[ni] = *(const i32x4*)(S2 + b_off[ni]);
#pragma unroll
        for (int mi = 0; mi < 4; ++mi) aC[mi] = *(const i32x4*)(S2 + a_off[mi]);
        sgb<0x30, 2>();
#pragma unroll
        for (int g = 0; g < 8; ++g) { sgb<0x8, 1>(); sgb<0x100, 1>(); }
        sgb<0x8, 8>();
        __builtin_amdgcn_s_setprio(0);
        __builtin_amdgcn_sched_barrier(0);
        bar();
    }
    asm volatile("s_waitcnt vmcnt(0)" ::: "memory");  // drain clamped tail DMAs

    // ---- epilogue: dequant + bias ----
    // 16x16 C/D layout: col = lane&15, row = (lane>>4)*4 + reg
    const int l15 = lane & 15, lq = lane >> 4;
#pragma unroll
    for (int mi = 0; mi < 8; ++mi) {
        const int rbase = bm0 + wr * 128 + mi * 16 + lq * 4;
        float xsv[4];
#pragma unroll
        for (int j = 0; j < 4; ++j) xsv[j] = xscale[rbase + j];
#pragma unroll
        for (int ni = 0; ni < 4; ++ni) {
            const int col = bn0 + wc * 64 + ni * 16 + l15;
            const float wsc = wscale[col];
            const float bv  = bias[col];
#pragma unroll
            for (int j = 0; j < 4; ++j) {
                out[(size_t)(rbase + j) * OUT_F + col] =
                    (float)acc[mi][ni][j] * xsv[j] * wsc + bv;
            }
        }
    }
}

extern "C" void kernel_launch(void* const* d_in, const int* in_sizes, int n_in,
                              void* d_out, int out_size, void* d_ws, size_t ws_size,
                              hipStream_t stream) {
    const float* x      = (const float*)d_in[0];
    const int*   w      = (const int*)d_in[1];     // int8 weights held as int32
    const float* wscale = (const float*)d_in[2];
    const float* bias   = (const float*)d_in[3];
    float* out = (float*)d_out;

    char* ws = (char*)d_ws;
    signed char* xq  = (signed char*)ws;                                   // 33.5 MB
    signed char* wq8 = (signed char*)(ws + (size_t)TOKENS * IN_F);         // 16.8 MB
    float* xscale    = (float*)(ws + (size_t)TOKENS * IN_F + (size_t)OUT_F * IN_F);

    (void)hipFuncSetAttribute((const void*)gemm_kernel,
                              hipFuncAttributeMaxDynamicSharedMemorySize, LDS_TOTAL);

    quant_x_kernel<<<TOKENS, 256, 0, stream>>>(x, xq, xscale);
    pack_w_kernel<<<(OUT_F * (IN_F / 16)) / 256, 256, 0, stream>>>(w, wq8);
    gemm_kernel<<<(TOKENS / 256) * (OUT_F / 256), 512, LDS_TOTAL, stream>>>(
        xq, wq8, xscale, wscale, bias, out);
}